// Round 6
// baseline (1488.678 us; speedup 1.0000x reference)
//
#include <hip/hip_runtime.h>
#include <cstdint>
#include <cstddef>

#define GN   16384
#define GIN  128
#define GOUT 64
#define NCH  16         // column chunks (width 1024)
#define LOG2E 1.44269504088896340736f

typedef __attribute__((ext_vector_type(8))) short short8;
typedef __attribute__((ext_vector_type(4))) float f32x4;
typedef __attribute__((ext_vector_type(4))) int   int4v;

__device__ __forceinline__ unsigned short f2bf(float f) {
  unsigned u = __float_as_uint(f);
  return (unsigned short)((u + 0x8000u) >> 16);   // round-half-up (cheap)
}

__device__ __forceinline__ unsigned short f2bf_rne(float f) {
  unsigned u = __float_as_uint(f);
  u += 0x7FFFu + ((u >> 16) & 1u);
  return (unsigned short)(u >> 16);
}

// ---------------------------------------------------------------------------
// mask: adj (int32, 1.07 GB) -> byte mask (33.5 MB), fully sequential stream.
//   msk[b] bit t = (adj[b*8 + t] != 0)
// ---------------------------------------------------------------------------
__global__ __launch_bounds__(256) void mask_kernel(
    const int* __restrict__ adj, unsigned char* __restrict__ msk)
{
  const unsigned nb = (unsigned)((size_t)GN * (size_t)GN / 8);  // 33,554,432
  const unsigned stride = gridDim.x * 256;
  for (unsigned b = blockIdx.x * 256 + threadIdx.x; b < nb; b += stride) {
    const int4v* p = (const int4v*)(adj + (size_t)b * 8);
    int4v x0 = __builtin_nontemporal_load(p);
    int4v x1 = __builtin_nontemporal_load(p + 1);
    unsigned by = (unsigned)(x0.x != 0)
                | ((unsigned)(x0.y != 0) << 1)
                | ((unsigned)(x0.z != 0) << 2)
                | ((unsigned)(x0.w != 0) << 3)
                | ((unsigned)(x1.x != 0) << 4)
                | ((unsigned)(x1.y != 0) << 5)
                | ((unsigned)(x1.z != 0) << 6)
                | ((unsigned)(x1.w != 0) << 7);
    msk[b] = (unsigned char)by;                  // regular store: stays in L2/L3
  }
}

// ---------------------------------------------------------------------------
// prep (verified): Wh = x@W, f_src/f_dst (x log2e), Wh packed in MFMA
// B-fragment order. wpk TRUE footprint = 512 tiles * 4096 ushorts = 4 MB.
// ---------------------------------------------------------------------------
__global__ __launch_bounds__(256) void prep_kernel(
    const float* __restrict__ x, const float* __restrict__ w,
    const float* __restrict__ aw, unsigned short* __restrict__ wpk,
    float* __restrict__ fs2, float* __restrict__ fd2)
{
  __shared__ float ws[GIN * GOUT];          // 32 KB
  __shared__ float red[2][64][4];

  const int t = threadIdx.x;
  const int rb = blockIdx.x * 64;

  for (int i = t; i < (GIN * GOUT) / 4; i += 256)
    ((float4*)ws)[i] = ((const float4*)w)[i];
  __syncthreads();

  const int r = t & 63, s = t >> 6;
  const int row = rb + r;
  const float* xr = x + (size_t)row * GIN;

  float acc[16];
#pragma unroll
  for (int d = 0; d < 16; ++d) acc[d] = 0.f;

  for (int kk = 0; kk < GIN; kk += 4) {
    float4 xv = *(const float4*)(xr + kk);
    float xa[4] = {xv.x, xv.y, xv.z, xv.w};
#pragma unroll
    for (int u = 0; u < 4; ++u) {
#pragma unroll
      for (int d = 0; d < 16; ++d)
        acc[d] += xa[u] * ws[(kk + u) * GOUT + s * 16 + d];
    }
  }

  const int jc = row >> 5;
  const int qq = (row & 31) >> 3;
  const int tt = row & 7;
  float psrc = 0.f, pdst = 0.f;
#pragma unroll
  for (int d = 0; d < 16; ++d) {
    const int dg = s * 16 + d;
    psrc += acc[d] * aw[dg];
    pdst += acc[d] * aw[GOUT + dg];
    const int f = dg >> 4, n = dg & 15;
    wpk[(size_t)jc * 4096 + f * 1024 + (qq * 16 + n) * 8 + tt] = f2bf_rne(acc[d]);
  }
  red[0][r][s] = psrc;
  red[1][r][s] = pdst;
  __syncthreads();
  if (s == 0) {
    float a_ = red[0][r][0] + red[0][r][1] + red[0][r][2] + red[0][r][3];
    float b_ = red[1][r][0] + red[1][r][1] + red[1][r][2] + red[1][r][3];
    fs2[row] = a_ * LOG2E;
    fd2[row] = b_ * LOG2E;
  }
}

// ---------------------------------------------------------------------------
// main v11: occupancy + pipeline attack (v10 was latency-bound at 2 waves/SIMD
// with a serialized per-step chain; removing DRAM traffic barely helped).
//  - 32 rows/wave (2 A-frag groups) -> acc 40 VGPR, target 4 waves/SIMD
//  - NCH=16 -> 8192 waves, 32 steps each
//  - 2-phase prefetch of latency-critical loads (mask gather + fd2);
//    B-fragments loaded in-step (L2 latency hides under pcalc VALU)
// Numeric path identical to verified v10.
// ---------------------------------------------------------------------------
__global__ __launch_bounds__(256, 4) void gat_main(
    const unsigned* __restrict__ bmw, const unsigned short* __restrict__ wpk,
    const float* __restrict__ fs2, const float* __restrict__ fd2,
    float* __restrict__ nump, float* __restrict__ denp)
{
  const int wave  = blockIdx.x * 4 + (threadIdx.x >> 6);
  const int lane  = threadIdx.x & 63;
  const int strip = wave & 511;             // 512 strips of 32 rows
  const int chunk = wave >> 9;              // 16 column chunks
  const int m = lane & 15;
  const int q = lane >> 4;
  const int q8 = q << 3;

  int   row0 = strip * 32 + m;              // group 0 row
  int   row1 = row0 + 16;                   // group 1 row
  float fs0 = fs2[row0];
  float fs1 = fs2[row1];
  const unsigned* __restrict__ bmr0 = bmw + (size_t)row0 * (GN / 32);
  const unsigned* __restrict__ bmr1 = bmw + (size_t)row1 * (GN / 32);

  const int CW = GN / NCH;                  // 1024 columns per chunk
  const int j0 = chunk * CW;
  const float4* __restrict__ fdv  = (const float4*)fd2;
  const short8* __restrict__ wpk8 = (const short8*)wpk;

  f32x4 acc0[4], acc1[4];
  f32x4 accd0, accd1;
  accd0 = (f32x4){0.f, 0.f, 0.f, 0.f};
  accd1 = (f32x4){0.f, 0.f, 0.f, 0.f};
#pragma unroll
  for (int b = 0; b < 4; ++b) {
    acc0[b] = (f32x4){0.f, 0.f, 0.f, 0.f};
    acc1[b] = (f32x4){0.f, 0.f, 0.f, 0.f};
  }

  short8 b_ones;
#pragma unroll
  for (int i = 0; i < 8; ++i) b_ones[i] = (short)0x3F80;  // bf16 1.0

  auto pelem = [&](unsigned byte, int t, float fd, float fsv) -> unsigned short {
    float sv = fsv + fd;
    float lv = fmaxf(sv, 0.02f * sv);       // lrelu (commutes with *log2e)
    float pe = __builtin_amdgcn_exp2f(lv);
    pe = (byte & (1u << t)) ? pe : 0.f;
    return f2bf(pe);
  };

  auto mk_af = [&](unsigned byte, float4 fA, float4 fB, float fsv) -> short8 {
    short8 af;
    af[0] = (short)pelem(byte, 0, fA.x, fsv);
    af[1] = (short)pelem(byte, 1, fA.y, fsv);
    af[2] = (short)pelem(byte, 2, fA.z, fsv);
    af[3] = (short)pelem(byte, 3, fA.w, fsv);
    af[4] = (short)pelem(byte, 4, fB.x, fsv);
    af[5] = (short)pelem(byte, 5, fB.y, fsv);
    af[6] = (short)pelem(byte, 6, fB.z, fsv);
    af[7] = (short)pelem(byte, 7, fB.w, fsv);
    return af;
  };

  // prefetch state (latency-critical loads only: mask words + fd2)
  auto LOADSTEP = [&](int j, unsigned& w0, unsigned& w1, float4& g0, float4& g1) {
    const int wi = j >> 5;
    const int i4 = (j >> 2) + (q << 1);
    w0 = bmr0[wi];
    w1 = bmr1[wi];
    g0 = fdv[i4];
    g1 = fdv[i4 + 1];
  };

  auto COMPS = [&](int j, unsigned w0, unsigned w1, float4 g0, float4 g1) {
    const int wi = j >> 5;
    // B fragments in-step: 4 contiguous 1 KB wave-loads from L2-resident wpk;
    // latency hides under the pcalc VALU block below (no dependency).
    const short8* wb = wpk8 + (size_t)wi * 512 + lane;
    short8 b0 = wb[0];
    short8 b1 = wb[128];
    short8 b2 = wb[256];
    short8 b3 = wb[384];

    {
      const unsigned byte = (w0 >> q8) & 0xffu;
      short8 af = mk_af(byte, g0, g1, fs0);
      acc0[0] = __builtin_amdgcn_mfma_f32_16x16x32_bf16(af, b0, acc0[0], 0, 0, 0);
      acc0[1] = __builtin_amdgcn_mfma_f32_16x16x32_bf16(af, b1, acc0[1], 0, 0, 0);
      acc0[2] = __builtin_amdgcn_mfma_f32_16x16x32_bf16(af, b2, acc0[2], 0, 0, 0);
      acc0[3] = __builtin_amdgcn_mfma_f32_16x16x32_bf16(af, b3, acc0[3], 0, 0, 0);
      accd0   = __builtin_amdgcn_mfma_f32_16x16x32_bf16(af, b_ones, accd0, 0, 0, 0);
    }
    {
      const unsigned byte = (w1 >> q8) & 0xffu;
      short8 af = mk_af(byte, g0, g1, fs1);
      acc1[0] = __builtin_amdgcn_mfma_f32_16x16x32_bf16(af, b0, acc1[0], 0, 0, 0);
      acc1[1] = __builtin_amdgcn_mfma_f32_16x16x32_bf16(af, b1, acc1[1], 0, 0, 0);
      acc1[2] = __builtin_amdgcn_mfma_f32_16x16x32_bf16(af, b2, acc1[2], 0, 0, 0);
      acc1[3] = __builtin_amdgcn_mfma_f32_16x16x32_bf16(af, b3, acc1[3], 0, 0, 0);
      accd1   = __builtin_amdgcn_mfma_f32_16x16x32_bf16(af, b_ones, accd1, 0, 0, 0);
    }
  };

  unsigned wA0, wA1, wB0, wB1;
  float4 fA0, fA1, fB0, fB1;

  LOADSTEP(j0, wA0, wA1, fA0, fA1);
#pragma unroll 1
  for (int j = j0; j < j0 + CW; j += 64) {
    LOADSTEP(j + 32, wB0, wB1, fB0, fB1);
    COMPS(j, wA0, wA1, fA0, fA1);
    int jn = j + 64;
    jn = (jn < j0 + CW) ? jn : j0;          // last prefetch wraps (discarded)
    LOADSTEP(jn, wA0, wA1, fA0, fA1);
    COMPS(j + 32, wB0, wB1, fB0, fB1);
  }

  // epilogue: plain stores into this chunk's private slab (no atomics)
  float* np = nump + (size_t)chunk * GN * GOUT;
  float* dp = denp + (size_t)chunk * GN;
  {
    const int orow0 = strip * 32 + q * 4;            // group 0: C/D row=q*4+r, col=m
#pragma unroll
    for (int r = 0; r < 4; ++r) {
      float* nr = np + (size_t)(orow0 + r) * GOUT + m;
      __builtin_nontemporal_store(acc0[0][r], nr + 0);
      __builtin_nontemporal_store(acc0[1][r], nr + 16);
      __builtin_nontemporal_store(acc0[2][r], nr + 32);
      __builtin_nontemporal_store(acc0[3][r], nr + 48);
      if (m == 0) dp[orow0 + r] = accd0[r];
    }
  }
  {
    const int orow0 = strip * 32 + 16 + q * 4;       // group 1
#pragma unroll
    for (int r = 0; r < 4; ++r) {
      float* nr = np + (size_t)(orow0 + r) * GOUT + m;
      __builtin_nontemporal_store(acc1[0][r], nr + 0);
      __builtin_nontemporal_store(acc1[1][r], nr + 16);
      __builtin_nontemporal_store(acc1[2][r], nr + 32);
      __builtin_nontemporal_store(acc1[3][r], nr + 48);
      if (m == 0) dp[orow0 + r] = accd1[r];
    }
  }
}

// ---------------------------------------------------------------------------
// finalize: out = elu( (sum_c num_c) / (sum_c den_c) )
// ---------------------------------------------------------------------------
__global__ __launch_bounds__(256) void fin_kernel(
    const float* __restrict__ nump, const float* __restrict__ denp,
    float* __restrict__ out)
{
  const int g = blockIdx.x * 256 + threadIdx.x;
  if (g >= GN * GOUT) return;
  const int row = g >> 6;
  float s = 0.f, d = 0.f;
#pragma unroll
  for (int c = 0; c < NCH; ++c) {
    s += nump[(size_t)c * GN * GOUT + g];
    d += denp[(size_t)c * GN + row];
  }
  float v = s / d;
  out[g] = (v > 0.f) ? v : expm1f(v);
}

extern "C" void kernel_launch(void* const* d_in, const int* in_sizes, int n_in,
                              void* d_out, int out_size, void* d_ws, size_t ws_size,
                              hipStream_t stream) {
  const float* x   = (const float*)d_in[0];
  const int*   adj = (const int*)d_in[1];
  const float* w   = (const float*)d_in[2];
  const float* aw  = (const float*)d_in[3];
  float* out = (float*)d_out;

  // ws layout (floats): nump[16*N*64] | denp[16*N] | fs2[N] | fd2[N] |
  //                     wpk (512 tiles x 4096 ushorts = 4 MB TRUE extent) |
  //                     msk (N*N/8 bytes, 33.5 MB)
  float* nump = (float*)d_ws;
  float* denp = nump + (size_t)NCH * GN * GOUT;
  float* fs2  = denp + (size_t)NCH * GN;
  float* fd2  = fs2 + GN;
  unsigned short* wpk = (unsigned short*)(fd2 + GN);
  // wpk spans 512*4096 ushorts (tile stride 4096, half-used frag slots) = 4 MB.
  unsigned char* msk = (unsigned char*)(wpk + (size_t)512 * 4096);
  // ~106 MB of the ws; everything fully written before read -> no memset needed

  mask_kernel<<<2048, 256, 0, stream>>>(adj, msk);
  prep_kernel<<<GN / 64, 256, 0, stream>>>(x, w, aw, wpk, fs2, fd2);
  gat_main<<<(GN / 32) * NCH / 4, 256, 0, stream>>>((const unsigned*)msk, wpk, fs2, fd2, nump, denp);
  fin_kernel<<<(GN * GOUT) / 256, 256, 0, stream>>>(nump, denp, out);
}